// Round 1
// baseline (2822.099 us; speedup 1.0000x reference)
//
#include <hip/hip_runtime.h>

#define N_NODES 50000
#define N_EDGES 800000
#define D 128

// workspace layout (floats)
#define AGG_N   (N_NODES * D)            // 6,400,000
#define DEG_OFF (AGG_N)                  // 50,000 floats
#define WT1_OFF (AGG_N + N_NODES)        // 16,384 floats (16B aligned: off*4 % 16 == 0)
#define WT2_OFF (WT1_OFF + D * D)

// ---------------- transpose W (both layers in one launch) ----------------
__global__ void transpose2_kernel(const float* __restrict__ W1, const float* __restrict__ W2,
                                  float* __restrict__ Wt1, float* __restrict__ Wt2) {
    int idx = blockIdx.x * 256 + threadIdx.x;     // 0..32767
    const float* W = (idx < D * D) ? W1 : W2;
    float* Wt      = (idx < D * D) ? Wt1 : Wt2;
    int i = idx & (D * D - 1);
    int j = i >> 7;        // output row of W
    int k = i & 127;       // input col
    Wt[k * D + j] = W[j * D + k];
}

// ---------------- degree ----------------
__global__ void deg_kernel(const int* __restrict__ dst, float* __restrict__ deg) {
    int e = blockIdx.x * blockDim.x + threadIdx.x;
    if (e < N_EDGES) unsafeAtomicAdd(&deg[dst[e]], 1.0f);
}

__global__ void invdeg_kernel(float* __restrict__ deg) {
    int i = blockIdx.x * blockDim.x + threadIdx.x;
    if (i < N_NODES) deg[i] = 1.0f / (deg[i] + 1.0f);
}

// ---------------- edge scatter-add: agg[dst] += x[src] ----------------
// 32 threads per edge, float4 per thread (128 floats/row)
__global__ __launch_bounds__(256) void scatter_kernel(const float* __restrict__ x,
                                                      const int* __restrict__ src,
                                                      const int* __restrict__ dst,
                                                      float* __restrict__ agg) {
    long long g = (long long)blockIdx.x * blockDim.x + threadIdx.x;
    int e = (int)(g >> 5);
    int c = (int)(g & 31);
    if (e >= N_EDGES) return;
    int s = src[e];
    int d = dst[e];
    float4 v = ((const float4*)x)[(size_t)s * 32 + c];
    float* a = agg + (size_t)d * D + c * 4;
    unsafeAtomicAdd(a + 0, v.x);
    unsafeAtomicAdd(a + 1, v.y);
    unsafeAtomicAdd(a + 2, v.z);
    unsafeAtomicAdd(a + 3, v.w);
}

// ---------------- fused normalize + GEMM (+bias, optional ReLU) ----------------
// out[n][j] = act( ((agg[n]+xs[n]) * invd[n]) . Wt[:,j] + b[j] )
// Block: 256 threads, 32 nodes, full 128 cols (col-halves sequential -> in-place safe).
template <int RELU>
__global__ __launch_bounds__(256, 2) void sage_gemm_kernel(const float* __restrict__ agg,
                                                           const float* __restrict__ xs,
                                                           const float* __restrict__ invd,
                                                           const float* __restrict__ Wt,
                                                           const float* __restrict__ bias,
                                                           float* __restrict__ out) {
    __shared__ float xl[32 * 132];   // 32 nodes x 128, row stride 132 (pad, 16B-aligned)
    __shared__ float wl[128 * 64];   // one col-half of Wt: [k][jj]
    const int t = threadIdx.x;
    const int n0 = blockIdx.x * 32;

    // stage x = (agg + xs) * invd   (1024 float4)
#pragma unroll
    for (int i = 0; i < 4; ++i) {
        int idx = t + i * 256;
        int n = idx >> 5;
        int c = idx & 31;
        int node = n0 + n;
        float4 v = make_float4(0.f, 0.f, 0.f, 0.f);
        if (node < N_NODES) {
            float4 a4 = ((const float4*)agg)[(size_t)node * 32 + c];
            float4 s4 = ((const float4*)xs)[(size_t)node * 32 + c];
            float iv = invd[node];
            v.x = (a4.x + s4.x) * iv;
            v.y = (a4.y + s4.y) * iv;
            v.z = (a4.z + s4.z) * iv;
            v.w = (a4.w + s4.w) * iv;
        }
        *(float4*)(&xl[n * 132 + c * 4]) = v;
    }

    const int j = t & 15;    // col-group: cols 4j..4j+3 (within a 64-col half)
    const int nr = t >> 4;   // nodes nr and nr+16

    float acc[2][2][4];

#pragma unroll
    for (int h = 0; h < 2; ++h) {
        __syncthreads();   // xl ready (h=0) / previous-half wl readers done (h=1)
        // stage Wt col-half h: wl[k*64 + jj] = Wt[k*128 + 64h + jj]
#pragma unroll
        for (int i = 0; i < 8; ++i) {
            int idx = t + i * 256;     // 2048 float4
            int k = idx >> 4;
            int c = idx & 15;
            *(float4*)(&wl[k * 64 + c * 4]) = ((const float4*)Wt)[k * 32 + h * 16 + c];
        }
        __syncthreads();

#pragma unroll
        for (int c = 0; c < 4; ++c) {
            float bv = bias[h * 64 + j * 4 + c];
            acc[h][0][c] = bv;
            acc[h][1][c] = bv;
        }

        for (int k = 0; k < 128; k += 4) {
            float4 x0 = *(const float4*)(&xl[nr * 132 + k]);
            float4 x1 = *(const float4*)(&xl[(nr + 16) * 132 + k]);
            const float* x0p = (const float*)&x0;
            const float* x1p = (const float*)&x1;
#pragma unroll
            for (int kk = 0; kk < 4; ++kk) {
                float4 w = *(const float4*)(&wl[(k + kk) * 64 + j * 4]);
                float xa = x0p[kk];
                float xb = x1p[kk];
                acc[h][0][0] += xa * w.x;
                acc[h][0][1] += xa * w.y;
                acc[h][0][2] += xa * w.z;
                acc[h][0][3] += xa * w.w;
                acc[h][1][0] += xb * w.x;
                acc[h][1][1] += xb * w.y;
                acc[h][1][2] += xb * w.z;
                acc[h][1][3] += xb * w.w;
            }
        }
    }

    // write 32 nodes x 128 cols; all LDS reads complete, in-place safe
#pragma unroll
    for (int r = 0; r < 2; ++r) {
        int node = n0 + nr + 16 * r;
        if (node >= N_NODES) continue;
#pragma unroll
        for (int h = 0; h < 2; ++h) {
            float4 o;
            o.x = acc[h][r][0];
            o.y = acc[h][r][1];
            o.z = acc[h][r][2];
            o.w = acc[h][r][3];
            if (RELU) {
                o.x = fmaxf(o.x, 0.f);
                o.y = fmaxf(o.y, 0.f);
                o.z = fmaxf(o.z, 0.f);
                o.w = fmaxf(o.w, 0.f);
            }
            ((float4*)out)[(size_t)node * 32 + h * 16 + j] = o;
        }
    }
}

extern "C" void kernel_launch(void* const* d_in, const int* in_sizes, int n_in,
                              void* d_out, int out_size, void* d_ws, size_t ws_size,
                              hipStream_t stream) {
    const float* h  = (const float*)d_in[0];
    const int*   ei = (const int*)d_in[1];
    const float* W1 = (const float*)d_in[2];
    const float* b1 = (const float*)d_in[3];
    const float* W2 = (const float*)d_in[4];
    const float* b2 = (const float*)d_in[5];
    float* out = (float*)d_out;
    float* ws  = (float*)d_ws;

    float* agg = ws;
    float* deg = ws + DEG_OFF;   // becomes inv_deg after invdeg_kernel
    float* Wt1 = ws + WT1_OFF;
    float* Wt2 = ws + WT2_OFF;
    const int* src = ei;
    const int* dst = ei + N_EDGES;

    // zero agg + deg
    hipMemsetAsync(agg, 0, (size_t)(AGG_N + N_NODES) * sizeof(float), stream);

    transpose2_kernel<<<128, 256, 0, stream>>>(W1, W2, Wt1, Wt2);
    deg_kernel<<<(N_EDGES + 255) / 256, 256, 0, stream>>>(dst, deg);
    invdeg_kernel<<<(N_NODES + 255) / 256, 256, 0, stream>>>(deg);

    // ---- layer 1 ----
    scatter_kernel<<<(int)(((long long)N_EDGES * 32 + 255) / 256), 256, 0, stream>>>(h, src, dst, agg);
    sage_gemm_kernel<1><<<(N_NODES + 31) / 32, 256, 0, stream>>>(agg, h, deg, Wt1, b1, out);

    // ---- layer 2 ----
    hipMemsetAsync(agg, 0, (size_t)AGG_N * sizeof(float), stream);
    scatter_kernel<<<(int)(((long long)N_EDGES * 32 + 255) / 256), 256, 0, stream>>>(out, src, dst, agg);
    sage_gemm_kernel<0><<<(N_NODES + 31) / 32, 256, 0, stream>>>(agg, out, deg, Wt2, b2, out);
}

// Round 2
// 384.968 us; speedup vs baseline: 7.3307x; 7.3307x over previous
//
#include <hip/hip_runtime.h>

#define N_NODES 50000
#define N_EDGES 800000
#define D 128

// -------- workspace layout (element offsets) --------
// floats: h1[6,400,000] | invd[50,000] | Wt1[16,384] | Wt2[16,384]
// ints  : row_start[50,001] | cursor[50,000] | csr_src[800,000]
#define H1_OFF   0
#define INVD_OFF (N_NODES * D)                    // 6,400,000
#define WT1_OFF  (INVD_OFF + N_NODES)             // 6,450,000 (byte off %16==0)
#define WT2_OFF  (WT1_OFF + D * D)
#define INT_OFF  (WT2_OFF + D * D)                // start of int region (as float idx)

// ---------------- transpose W (both layers in one launch) ----------------
__global__ void transpose2_kernel(const float* __restrict__ W1, const float* __restrict__ W2,
                                  float* __restrict__ Wt1, float* __restrict__ Wt2) {
    int idx = blockIdx.x * 256 + threadIdx.x;     // 0..32767
    const float* W = (idx < D * D) ? W1 : W2;
    float* Wt      = (idx < D * D) ? Wt1 : Wt2;
    int i = idx & (D * D - 1);
    int j = i >> 7;
    int k = i & 127;
    Wt[k * D + j] = W[j * D + k];
}

// ---------------- CSR build ----------------
__global__ void count_kernel(const int* __restrict__ dst, int* __restrict__ cnt) {
    int e = blockIdx.x * blockDim.x + threadIdx.x;
    if (e < N_EDGES) atomicAdd(&cnt[dst[e]], 1);
}

// single block, 1024 threads: exclusive scan of cnt -> row_start & cursor; invd = 1/(cnt+1)
__global__ __launch_bounds__(1024) void scan_kernel(int* __restrict__ cnt_cursor,
                                                    int* __restrict__ row_start,
                                                    float* __restrict__ invd) {
    __shared__ int buf[1024];
    __shared__ int carry_s;
    int t = threadIdx.x;
    if (t == 0) carry_s = 0;
    __syncthreads();
    for (int base = 0; base < N_NODES; base += 1024) {
        int i = base + t;
        int v = (i < N_NODES) ? cnt_cursor[i] : 0;
        buf[t] = v;
        __syncthreads();
        for (int off = 1; off < 1024; off <<= 1) {
            int add = (t >= off) ? buf[t - off] : 0;
            __syncthreads();
            buf[t] += add;
            __syncthreads();
        }
        int incl = buf[t];
        int carry = carry_s;
        if (i < N_NODES) {
            int excl = carry + incl - v;
            row_start[i] = excl;
            cnt_cursor[i] = excl;
            invd[i] = 1.0f / (float)(v + 1);
        }
        __syncthreads();
        if (t == 1023) carry_s = carry + incl;
        __syncthreads();
    }
    if (t == 0) row_start[N_NODES] = N_EDGES;
}

__global__ void fill_kernel(const int* __restrict__ src, const int* __restrict__ dst,
                            int* __restrict__ cursor, int* __restrict__ csr_src) {
    int e = blockIdx.x * blockDim.x + threadIdx.x;
    if (e < N_EDGES) {
        int d = dst[e];
        int pos = atomicAdd(&cursor[d], 1);
        csr_src[pos] = src[e];
    }
}

// ---------------- fused gather-aggregate + normalize + GEMM ----------------
// Block: 256 threads, 32 nodes. Phase A: each 32-lane group gathers 4 nodes'
// in-edge rows (CSR), adds self, scales by invd, stages to LDS. Phase B: GEMM.
template <int RELU>
__global__ __launch_bounds__(256, 2) void sage_fused_kernel(const float* __restrict__ x,
                                                            const int* __restrict__ row_start,
                                                            const int* __restrict__ csr_src,
                                                            const float* __restrict__ invd,
                                                            const float* __restrict__ Wt,
                                                            const float* __restrict__ bias,
                                                            float* __restrict__ out) {
    __shared__ float xl[32 * 132];   // 32 nodes x 128, stride 132
    __shared__ float wl[128 * 64];   // one col-half of Wt: [k][jj]
    const int t = threadIdx.x;
    const int n0 = blockIdx.x * 32;
    const int g = t >> 5;            // group 0..7
    const int c = t & 31;            // float4 column

    // Phase A: gather + aggregate 4 nodes per group
#pragma unroll
    for (int q = 0; q < 4; ++q) {
        int n = g * 4 + q;
        int node = n0 + n;
        float4 acc = make_float4(0.f, 0.f, 0.f, 0.f);
        if (node < N_NODES) {
            acc = ((const float4*)x)[(size_t)node * 32 + c];   // self
            int e0 = row_start[node];
            int e1 = row_start[node + 1];
            int e = e0;
            int nb = e0 + ((e1 - e0) & ~3);
            for (; e < nb; e += 4) {   // 4 independent gathers per step
                int s0 = csr_src[e + 0];
                int s1 = csr_src[e + 1];
                int s2 = csr_src[e + 2];
                int s3 = csr_src[e + 3];
                float4 v0 = ((const float4*)x)[(size_t)s0 * 32 + c];
                float4 v1 = ((const float4*)x)[(size_t)s1 * 32 + c];
                float4 v2 = ((const float4*)x)[(size_t)s2 * 32 + c];
                float4 v3 = ((const float4*)x)[(size_t)s3 * 32 + c];
                acc.x += (v0.x + v1.x) + (v2.x + v3.x);
                acc.y += (v0.y + v1.y) + (v2.y + v3.y);
                acc.z += (v0.z + v1.z) + (v2.z + v3.z);
                acc.w += (v0.w + v1.w) + (v2.w + v3.w);
            }
            for (; e < e1; ++e) {
                int s = csr_src[e];
                float4 v = ((const float4*)x)[(size_t)s * 32 + c];
                acc.x += v.x; acc.y += v.y; acc.z += v.z; acc.w += v.w;
            }
            float iv = invd[node];
            acc.x *= iv; acc.y *= iv; acc.z *= iv; acc.w *= iv;
        }
        *(float4*)(&xl[n * 132 + c * 4]) = acc;
    }

    const int j = t & 15;    // col-group within 64-col half
    const int nr = t >> 4;   // nodes nr, nr+16

    float acc[2][2][4];

#pragma unroll
    for (int h = 0; h < 2; ++h) {
        __syncthreads();   // xl ready (h=0) / previous-half wl readers done (h=1)
#pragma unroll
        for (int i = 0; i < 8; ++i) {
            int idx = t + i * 256;     // 2048 float4
            int k = idx >> 4;
            int cc = idx & 15;
            *(float4*)(&wl[k * 64 + cc * 4]) = ((const float4*)Wt)[k * 32 + h * 16 + cc];
        }
        __syncthreads();

#pragma unroll
        for (int cc = 0; cc < 4; ++cc) {
            float bv = bias[h * 64 + j * 4 + cc];
            acc[h][0][cc] = bv;
            acc[h][1][cc] = bv;
        }

        for (int k = 0; k < 128; k += 4) {
            float4 x0 = *(const float4*)(&xl[nr * 132 + k]);
            float4 x1 = *(const float4*)(&xl[(nr + 16) * 132 + k]);
            const float* x0p = (const float*)&x0;
            const float* x1p = (const float*)&x1;
#pragma unroll
            for (int kk = 0; kk < 4; ++kk) {
                float4 w = *(const float4*)(&wl[(k + kk) * 64 + j * 4]);
                float xa = x0p[kk];
                float xb = x1p[kk];
                acc[h][0][0] += xa * w.x;
                acc[h][0][1] += xa * w.y;
                acc[h][0][2] += xa * w.z;
                acc[h][0][3] += xa * w.w;
                acc[h][1][0] += xb * w.x;
                acc[h][1][1] += xb * w.y;
                acc[h][1][2] += xb * w.z;
                acc[h][1][3] += xb * w.w;
            }
        }
    }

#pragma unroll
    for (int r = 0; r < 2; ++r) {
        int node = n0 + nr + 16 * r;
        if (node >= N_NODES) continue;
#pragma unroll
        for (int h = 0; h < 2; ++h) {
            float4 o;
            o.x = acc[h][r][0];
            o.y = acc[h][r][1];
            o.z = acc[h][r][2];
            o.w = acc[h][r][3];
            if (RELU) {
                o.x = fmaxf(o.x, 0.f);
                o.y = fmaxf(o.y, 0.f);
                o.z = fmaxf(o.z, 0.f);
                o.w = fmaxf(o.w, 0.f);
            }
            ((float4*)out)[(size_t)node * 32 + h * 16 + j] = o;
        }
    }
}

extern "C" void kernel_launch(void* const* d_in, const int* in_sizes, int n_in,
                              void* d_out, int out_size, void* d_ws, size_t ws_size,
                              hipStream_t stream) {
    const float* h  = (const float*)d_in[0];
    const int*   ei = (const int*)d_in[1];
    const float* W1 = (const float*)d_in[2];
    const float* b1 = (const float*)d_in[3];
    const float* W2 = (const float*)d_in[4];
    const float* b2 = (const float*)d_in[5];
    float* out = (float*)d_out;
    float* ws  = (float*)d_ws;

    float* h1   = ws + H1_OFF;
    float* invd = ws + INVD_OFF;
    float* Wt1  = ws + WT1_OFF;
    float* Wt2  = ws + WT2_OFF;
    int* ints      = (int*)(ws + INT_OFF);
    int* row_start = ints;                       // N_NODES+1
    int* cursor    = ints + (N_NODES + 1);       // N_NODES (counts, then fill cursors)
    int* csr_src   = ints + (2 * N_NODES + 1);   // N_EDGES

    const int* src = ei;
    const int* dst = ei + N_EDGES;

    // zero edge counts
    hipMemsetAsync(cursor, 0, (size_t)N_NODES * sizeof(int), stream);

    transpose2_kernel<<<128, 256, 0, stream>>>(W1, W2, Wt1, Wt2);
    count_kernel<<<(N_EDGES + 255) / 256, 256, 0, stream>>>(dst, cursor);
    scan_kernel<<<1, 1024, 0, stream>>>(cursor, row_start, invd);
    fill_kernel<<<(N_EDGES + 255) / 256, 256, 0, stream>>>(src, dst, cursor, csr_src);

    // layer 1: h -> h1 (ReLU)
    sage_fused_kernel<1><<<(N_NODES + 31) / 32, 256, 0, stream>>>(h, row_start, csr_src, invd, Wt1, b1, h1);
    // layer 2: h1 -> out
    sage_fused_kernel<0><<<(N_NODES + 31) / 32, 256, 0, stream>>>(h1, row_start, csr_src, invd, Wt2, b2, out);
}

// Round 3
// 272.108 us; speedup vs baseline: 10.3712x; 1.4148x over previous
//
#include <hip/hip_runtime.h>

#define N_NODES 50000
#define N_EDGES 800000
#define D 128
#define N4 (N_NODES / 4)          // 12500 int4 groups (N_NODES % 4 == 0)
#define NBLK_SCAN ((N4 + 255) / 256)   // 49

// -------- workspace layout (element offsets) --------
// floats: h1[6,400,000] | invd[50,000] | Wt1[16,384] | Wt2[16,384] | int region
#define H1_OFF   0
#define INVD_OFF (N_NODES * D)
#define WT1_OFF  (INVD_OFF + N_NODES)
#define WT2_OFF  (WT1_OFF + D * D)
#define INT_OFF  (WT2_OFF + D * D)
// ints (relative to int base, which is 16B-aligned):
// row_start[50001] (pad to 50004) | cursor[50000] | csr_src[800000] | blocksum[64]
#define RS_OFF   0
#define CUR_OFF  50004
#define CSR_OFF  (CUR_OFF + N_NODES)
#define BS_OFF   (CSR_OFF + N_EDGES)

// ---------------- transpose W (both layers in one launch) ----------------
__global__ void transpose2_kernel(const float* __restrict__ W1, const float* __restrict__ W2,
                                  float* __restrict__ Wt1, float* __restrict__ Wt2) {
    int idx = blockIdx.x * 256 + threadIdx.x;     // 0..32767
    const float* W = (idx < D * D) ? W1 : W2;
    float* Wt      = (idx < D * D) ? Wt1 : Wt2;
    int i = idx & (D * D - 1);
    int j = i >> 7;
    int k = i & 127;
    Wt[k * D + j] = W[j * D + k];
}

// ---------------- CSR build ----------------
__global__ void count_kernel(const int* __restrict__ dst, int* __restrict__ cnt) {
    int e = blockIdx.x * blockDim.x + threadIdx.x;
    if (e < N_EDGES) atomicAdd(&cnt[dst[e]], 1);
}

// phase 1: per-block (1024 elements) sums
__global__ __launch_bounds__(256) void partial_kernel(const int* __restrict__ cnt,
                                                      int* __restrict__ blocksum) {
    __shared__ int red[4];
    int t = threadIdx.x;
    int i4 = blockIdx.x * 256 + t;
    int s = 0;
    if (i4 < N4) {
        int4 v = ((const int4*)cnt)[i4];
        s = v.x + v.y + v.z + v.w;
    }
#pragma unroll
    for (int off = 1; off < 64; off <<= 1) s += __shfl_xor(s, off, 64);
    if ((t & 63) == 0) red[t >> 6] = s;
    __syncthreads();
    if (t == 0) blocksum[blockIdx.x] = red[0] + red[1] + red[2] + red[3];
}

// phase 2: single wave scans the 49 block sums -> exclusive
__global__ __launch_bounds__(64) void scanblk_kernel(int* __restrict__ blocksum) {
    __shared__ int buf[64];
    int t = threadIdx.x;
    int v = (t < NBLK_SCAN) ? blocksum[t] : 0;
    buf[t] = v;
    __syncthreads();
#pragma unroll
    for (int off = 1; off < 64; off <<= 1) {
        int a = (t >= off) ? buf[t - off] : 0;
        __syncthreads();
        buf[t] += a;
        __syncthreads();
    }
    if (t < NBLK_SCAN) blocksum[t] = buf[t] - v;
}

// phase 3: write row_start / cursor / invd
__global__ __launch_bounds__(256) void write_kernel(int* __restrict__ cnt_cursor,
                                                    const int* __restrict__ blocksum,
                                                    int* __restrict__ row_start,
                                                    float* __restrict__ invd) {
    __shared__ int tsum[256];
    int t = threadIdx.x;
    int i4 = blockIdx.x * 256 + t;
    int4 v = make_int4(0, 0, 0, 0);
    bool act = (i4 < N4);
    if (act) v = ((const int4*)cnt_cursor)[i4];
    int s = v.x + v.y + v.z + v.w;
    tsum[t] = s;
    __syncthreads();
#pragma unroll
    for (int off = 1; off < 256; off <<= 1) {
        int a = (t >= off) ? tsum[t - off] : 0;
        __syncthreads();
        tsum[t] += a;
        __syncthreads();
    }
    int excl = blocksum[blockIdx.x] + tsum[t] - s;
    if (act) {
        int4 rs;
        rs.x = excl;
        rs.y = rs.x + v.x;
        rs.z = rs.y + v.y;
        rs.w = rs.z + v.z;
        ((int4*)row_start)[i4] = rs;
        ((int4*)cnt_cursor)[i4] = rs;   // cursor = exclusive start
        int i = i4 * 4;
        invd[i + 0] = 1.0f / (float)(v.x + 1);
        invd[i + 1] = 1.0f / (float)(v.y + 1);
        invd[i + 2] = 1.0f / (float)(v.z + 1);
        invd[i + 3] = 1.0f / (float)(v.w + 1);
    }
    if (i4 == 0) row_start[N_NODES] = N_EDGES;
}

__global__ void fill_kernel(const int* __restrict__ src, const int* __restrict__ dst,
                            int* __restrict__ cursor, int* __restrict__ csr_src) {
    int e = blockIdx.x * blockDim.x + threadIdx.x;
    if (e < N_EDGES) {
        int d = dst[e];
        int pos = atomicAdd(&cursor[d], 1);
        csr_src[pos] = src[e];
    }
}

// ---------------- fused gather-aggregate + normalize + GEMM ----------------
template <int RELU>
__global__ __launch_bounds__(256, 3) void sage_fused_kernel(const float* __restrict__ x,
                                                            const int* __restrict__ row_start,
                                                            const int* __restrict__ csr_src,
                                                            const float* __restrict__ invd,
                                                            const float* __restrict__ Wt,
                                                            const float* __restrict__ bias,
                                                            float* __restrict__ out) {
    __shared__ float xl[32 * 132];   // 32 nodes x 128, stride 132
    __shared__ float wl[128 * 64];   // one col-half of Wt: [k][jj]
    const int t = threadIdx.x;
    const int n0 = blockIdx.x * 32;
    const int g = t >> 5;            // group 0..7
    const int c = t & 31;            // float4 column

    // Phase A: gather + aggregate 4 nodes per group (unroll 8 for MLP)
#pragma unroll
    for (int q = 0; q < 4; ++q) {
        int n = g * 4 + q;
        int node = n0 + n;
        float4 acc = make_float4(0.f, 0.f, 0.f, 0.f);
        if (node < N_NODES) {
            acc = ((const float4*)x)[(size_t)node * 32 + c];   // self
            int e0 = row_start[node];
            int e1 = row_start[node + 1];
            int e = e0;
            int nb = e0 + ((e1 - e0) & ~7);
            for (; e < nb; e += 8) {
                int s0 = csr_src[e + 0];
                int s1 = csr_src[e + 1];
                int s2 = csr_src[e + 2];
                int s3 = csr_src[e + 3];
                int s4 = csr_src[e + 4];
                int s5 = csr_src[e + 5];
                int s6 = csr_src[e + 6];
                int s7 = csr_src[e + 7];
                float4 v0 = ((const float4*)x)[(size_t)s0 * 32 + c];
                float4 v1 = ((const float4*)x)[(size_t)s1 * 32 + c];
                float4 v2 = ((const float4*)x)[(size_t)s2 * 32 + c];
                float4 v3 = ((const float4*)x)[(size_t)s3 * 32 + c];
                float4 v4 = ((const float4*)x)[(size_t)s4 * 32 + c];
                float4 v5 = ((const float4*)x)[(size_t)s5 * 32 + c];
                float4 v6 = ((const float4*)x)[(size_t)s6 * 32 + c];
                float4 v7 = ((const float4*)x)[(size_t)s7 * 32 + c];
                acc.x += ((v0.x + v1.x) + (v2.x + v3.x)) + ((v4.x + v5.x) + (v6.x + v7.x));
                acc.y += ((v0.y + v1.y) + (v2.y + v3.y)) + ((v4.y + v5.y) + (v6.y + v7.y));
                acc.z += ((v0.z + v1.z) + (v2.z + v3.z)) + ((v4.z + v5.z) + (v6.z + v7.z));
                acc.w += ((v0.w + v1.w) + (v2.w + v3.w)) + ((v4.w + v5.w) + (v6.w + v7.w));
            }
            if (e1 - e >= 4) {
                int s0 = csr_src[e + 0];
                int s1 = csr_src[e + 1];
                int s2 = csr_src[e + 2];
                int s3 = csr_src[e + 3];
                float4 v0 = ((const float4*)x)[(size_t)s0 * 32 + c];
                float4 v1 = ((const float4*)x)[(size_t)s1 * 32 + c];
                float4 v2 = ((const float4*)x)[(size_t)s2 * 32 + c];
                float4 v3 = ((const float4*)x)[(size_t)s3 * 32 + c];
                acc.x += (v0.x + v1.x) + (v2.x + v3.x);
                acc.y += (v0.y + v1.y) + (v2.y + v3.y);
                acc.z += (v0.z + v1.z) + (v2.z + v3.z);
                acc.w += (v0.w + v1.w) + (v2.w + v3.w);
                e += 4;
            }
            for (; e < e1; ++e) {
                int s = csr_src[e];
                float4 v = ((const float4*)x)[(size_t)s * 32 + c];
                acc.x += v.x; acc.y += v.y; acc.z += v.z; acc.w += v.w;
            }
            float iv = invd[node];
            acc.x *= iv; acc.y *= iv; acc.z *= iv; acc.w *= iv;
        }
        *(float4*)(&xl[n * 132 + c * 4]) = acc;
    }

    const int j = t & 15;    // col-group within 64-col half
    const int nr = t >> 4;   // nodes nr, nr+16

    float acc[2][2][4];

#pragma unroll
    for (int h = 0; h < 2; ++h) {
        __syncthreads();   // xl ready (h=0) / previous-half wl readers done (h=1)
#pragma unroll
        for (int i = 0; i < 8; ++i) {
            int idx = t + i * 256;     // 2048 float4
            int k = idx >> 4;
            int cc = idx & 15;
            *(float4*)(&wl[k * 64 + cc * 4]) = ((const float4*)Wt)[k * 32 + h * 16 + cc];
        }
        __syncthreads();

#pragma unroll
        for (int cc = 0; cc < 4; ++cc) {
            float bv = bias[h * 64 + j * 4 + cc];
            acc[h][0][cc] = bv;
            acc[h][1][cc] = bv;
        }

        for (int k = 0; k < 128; k += 4) {
            float4 x0 = *(const float4*)(&xl[nr * 132 + k]);
            float4 x1 = *(const float4*)(&xl[(nr + 16) * 132 + k]);
            const float* x0p = (const float*)&x0;
            const float* x1p = (const float*)&x1;
#pragma unroll
            for (int kk = 0; kk < 4; ++kk) {
                float4 w = *(const float4*)(&wl[(k + kk) * 64 + j * 4]);
                float xa = x0p[kk];
                float xb = x1p[kk];
                acc[h][0][0] += xa * w.x;
                acc[h][0][1] += xa * w.y;
                acc[h][0][2] += xa * w.z;
                acc[h][0][3] += xa * w.w;
                acc[h][1][0] += xb * w.x;
                acc[h][1][1] += xb * w.y;
                acc[h][1][2] += xb * w.z;
                acc[h][1][3] += xb * w.w;
            }
        }
    }

#pragma unroll
    for (int r = 0; r < 2; ++r) {
        int node = n0 + nr + 16 * r;
        if (node >= N_NODES) continue;
#pragma unroll
        for (int h = 0; h < 2; ++h) {
            float4 o;
            o.x = acc[h][r][0];
            o.y = acc[h][r][1];
            o.z = acc[h][r][2];
            o.w = acc[h][r][3];
            if (RELU) {
                o.x = fmaxf(o.x, 0.f);
                o.y = fmaxf(o.y, 0.f);
                o.z = fmaxf(o.z, 0.f);
                o.w = fmaxf(o.w, 0.f);
            }
            ((float4*)out)[(size_t)node * 32 + h * 16 + j] = o;
        }
    }
}

extern "C" void kernel_launch(void* const* d_in, const int* in_sizes, int n_in,
                              void* d_out, int out_size, void* d_ws, size_t ws_size,
                              hipStream_t stream) {
    const float* h  = (const float*)d_in[0];
    const int*   ei = (const int*)d_in[1];
    const float* W1 = (const float*)d_in[2];
    const float* b1 = (const float*)d_in[3];
    const float* W2 = (const float*)d_in[4];
    const float* b2 = (const float*)d_in[5];
    float* out = (float*)d_out;
    float* ws  = (float*)d_ws;

    float* h1   = ws + H1_OFF;
    float* invd = ws + INVD_OFF;
    float* Wt1  = ws + WT1_OFF;
    float* Wt2  = ws + WT2_OFF;
    int* ints      = (int*)(ws + INT_OFF);
    int* row_start = ints + RS_OFF;
    int* cursor    = ints + CUR_OFF;
    int* csr_src   = ints + CSR_OFF;
    int* blocksum  = ints + BS_OFF;

    const int* src = ei;
    const int* dst = ei + N_EDGES;

    // zero edge counts (cursor doubles as count array)
    hipMemsetAsync(cursor, 0, (size_t)N_NODES * sizeof(int), stream);

    transpose2_kernel<<<128, 256, 0, stream>>>(W1, W2, Wt1, Wt2);
    count_kernel<<<(N_EDGES + 255) / 256, 256, 0, stream>>>(dst, cursor);
    partial_kernel<<<NBLK_SCAN, 256, 0, stream>>>(cursor, blocksum);
    scanblk_kernel<<<1, 64, 0, stream>>>(blocksum);
    write_kernel<<<NBLK_SCAN, 256, 0, stream>>>(cursor, blocksum, row_start, invd);
    fill_kernel<<<(N_EDGES + 255) / 256, 256, 0, stream>>>(src, dst, cursor, csr_src);

    // layer 1: h -> h1 (ReLU)
    sage_fused_kernel<1><<<(N_NODES + 31) / 32, 256, 0, stream>>>(h, row_start, csr_src, invd, Wt1, b1, h1);
    // layer 2: h1 -> out
    sage_fused_kernel<0><<<(N_NODES + 31) / 32, 256, 0, stream>>>(h1, row_start, csr_src, invd, Wt2, b2, out);
}